// Round 1
// baseline (8038.319 us; speedup 1.0000x reference)
//
#include <hip/hip_runtime.h>
#include <hip/hip_bf16.h>

#define NEG_SLOPE 0.01f
#define EPS_DEMOD 1e-8f

static __device__ __forceinline__ float leaky(float v) {
    return v > 0.0f ? v : v * NEG_SLOPE;
}

static __device__ __forceinline__ unsigned int bf16_bits_of(float f) {
    __hip_bfloat16 h = __float2bfloat16(f);
    unsigned short u;
    __builtin_memcpy(&u, &h, sizeof(u));
    return (unsigned int)u;
}

// -------------------------------------------------------------------------
// Style MLP + weight demodulation.
// Output layout: w_out[n][ci][tap][co64]  (float)
// -------------------------------------------------------------------------
__global__ void style_weights_kernel(
    const float* __restrict__ s,                                  // (2,64)
    const float* __restrict__ w1, const float* __restrict__ b1,   // (C1,64)
    const float* __restrict__ w2, const float* __restrict__ b2,   // (C2,C1)
    const float* __restrict__ w3, const float* __restrict__ b3,   // (Cm,C2)
    const float* __restrict__ wc,                                 // (64,Cm,taps)
    float* __restrict__ w_out,                                    // (2,Cm,taps,64)
    int C1, int C2, int Cm, int taps)
{
    const int n = blockIdx.x;
    const int tid = threadIdx.x;
    __shared__ float s_l[64];
    __shared__ float h1[128];
    __shared__ float h2[128];
    __shared__ float modv[64];
    __shared__ float red[256];
    __shared__ float scale_l[64];

    if (tid < 64) s_l[tid] = s[n * 64 + tid];
    __syncthreads();
    if (tid < C1) {
        float a = b1[tid];
        const float* wr = w1 + (size_t)tid * 64;
        for (int k = 0; k < 64; ++k) a = fmaf(s_l[k], wr[k], a);
        h1[tid] = leaky(a);
    }
    __syncthreads();
    if (tid < C2) {
        float a = b2[tid];
        const float* wr = w2 + (size_t)tid * C1;
        for (int k = 0; k < C1; ++k) a = fmaf(h1[k], wr[k], a);
        h2[tid] = leaky(a);
    }
    __syncthreads();
    if (tid < Cm) {
        float a = b3[tid];
        const float* wr = w3 + (size_t)tid * C2;
        for (int k = 0; k < C2; ++k) a = fmaf(h2[k], wr[k], a);
        modv[tid] = a;
    }
    __syncthreads();

    // demodulation: 64 co x 4 slices
    const int co = tid >> 2;
    const int sl = tid & 3;
    float ss = 0.0f;
    for (int ci = sl; ci < Cm; ci += 4) {
        float m = modv[ci];
        const float* wp = wc + ((size_t)co * Cm + ci) * taps;
        for (int t = 0; t < taps; ++t) {
            float v = wp[t] * m;
            ss = fmaf(v, v, ss);
        }
    }
    red[tid] = ss;
    __syncthreads();
    if (sl == 0) {
        float tot = red[tid] + red[tid + 1] + red[tid + 2] + red[tid + 3];
        scale_l[co] = rsqrtf(tot + EPS_DEMOD);
    }
    __syncthreads();
    {
        const float sc = scale_l[co];
        for (int ci = sl; ci < Cm; ci += 4) {
            float m = modv[ci] * sc;
            const float* wp = wc + ((size_t)co * Cm + ci) * taps;
            float* op = w_out + ((size_t)n * Cm + ci) * (size_t)taps * 64 + co;
            for (int t = 0; t < taps; ++t)
                op[(size_t)t * 64] = wp[t] * m;
        }
    }
}

// -------------------------------------------------------------------------
// c1: x f32 (2,32,96,96,96) -> h bf16 (2,64,94,94,94), 3x3x3, leaky
// block: 256 thr = 16 co-groups(x4 co) x 16 voxel-threads (4z x 4y, 8x each)
// -------------------------------------------------------------------------
__global__ void conv1_kernel(const float* __restrict__ x,
                             const float* __restrict__ wdm,   // (2,32,27,64)
                             const float* __restrict__ bias,  // (64,)
                             __hip_bfloat16* __restrict__ h)
{
    __shared__ float xt[4][6][6][12];
    __shared__ float wl[4][27][64];

    const int tid = threadIdx.x;
    const int co_t = tid >> 4;
    const int v_t = tid & 15;
    const int vz = v_t >> 2;
    const int vy = v_t & 3;

    const int x0 = blockIdx.x * 8;
    const int y0 = blockIdx.y * 4;
    const int n  = blockIdx.z / 24;
    const int z0 = (blockIdx.z % 24) * 4;

    float acc[4][8];
    #pragma unroll
    for (int c = 0; c < 4; ++c)
        #pragma unroll
        for (int j = 0; j < 8; ++j) acc[c][j] = 0.0f;

    const float* xn = x + (size_t)n * 32 * 96 * 96 * 96;

    #pragma unroll 1
    for (int c0 = 0; c0 < 32; c0 += 4) {
        __syncthreads();
        for (int idx = tid; idx < 4 * 6 * 6 * 12; idx += 256) {
            int ci_l = idx / 432;
            int r = idx - ci_l * 432;
            int zz = r / 72; r -= zz * 72;
            int yy = r / 12;
            int xx = r - yy * 12;
            int gz = z0 + zz, gy = y0 + yy, gx = x0 + xx;
            float v = 0.0f;
            if (gz < 96 && gy < 96 && gx < 96)
                v = xn[(((size_t)(c0 + ci_l) * 96 + gz) * 96 + gy) * 96 + gx];
            ((float*)xt)[idx] = v;
        }
        const float* wsrc = wdm + ((size_t)n * 32 + c0) * 27 * 64;
        for (int idx = tid; idx < 4 * 27 * 64; idx += 256)
            ((float*)wl)[idx] = wsrc[idx];
        __syncthreads();

        #pragma unroll 1
        for (int ci_l = 0; ci_l < 4; ++ci_l) {
            #pragma unroll
            for (int kd = 0; kd < 3; ++kd) {
                #pragma unroll
                for (int kh = 0; kh < 3; ++kh) {
                    const float4* row =
                        reinterpret_cast<const float4*>(&xt[ci_l][vz + kd][vy + kh][0]);
                    float4 r0 = row[0], r1 = row[1], r2 = row[2];
                    float xr[12] = {r0.x, r0.y, r0.z, r0.w,
                                    r1.x, r1.y, r1.z, r1.w,
                                    r2.x, r2.y, r2.z, r2.w};
                    const float* wrow = &wl[ci_l][(kd * 3 + kh) * 3][co_t * 4];
                    #pragma unroll
                    for (int kx = 0; kx < 3; ++kx) {
                        float4 wv = *reinterpret_cast<const float4*>(wrow + kx * 64);
                        #pragma unroll
                        for (int j = 0; j < 8; ++j) {
                            float xv = xr[kx + j];
                            acc[0][j] = fmaf(wv.x, xv, acc[0][j]);
                            acc[1][j] = fmaf(wv.y, xv, acc[1][j]);
                            acc[2][j] = fmaf(wv.z, xv, acc[2][j]);
                            acc[3][j] = fmaf(wv.w, xv, acc[3][j]);
                        }
                    }
                }
            }
        }
    }

    const int oz = z0 + vz, oy = y0 + vy;
    if (oz >= 94 || oy >= 94) return;
    const int co = co_t * 4;
    #pragma unroll
    for (int c = 0; c < 4; ++c) {
        float b = bias[co + c];
        size_t base = ((((size_t)n * 64 + co + c) * 94 + oz) * 94 + oy) * 94 + x0;
        if (x0 + 8 <= 94) {
            unsigned int* dst = reinterpret_cast<unsigned int*>(h + base);
            #pragma unroll
            for (int jp = 0; jp < 4; ++jp) {
                unsigned int lo = bf16_bits_of(leaky(acc[c][2 * jp] + b));
                unsigned int hi = bf16_bits_of(leaky(acc[c][2 * jp + 1] + b));
                dst[jp] = (hi << 16) | lo;
            }
        } else {
            for (int j = 0; j < 8 && x0 + j < 94; ++j)
                h[base + j] = __float2bfloat16(leaky(acc[c][j] + b));
        }
    }
}

// -------------------------------------------------------------------------
// c2: h bf16 (2,64,94,94,94) -> out f32 (2,64,92,92,92), 3x3x3,
//     + fused skip (1x1x1 conv of x, cropped) + biases + leaky
// -------------------------------------------------------------------------
__global__ void conv2_kernel(const __hip_bfloat16* __restrict__ hbuf,
                             const float* __restrict__ x,
                             const float* __restrict__ wdm,    // (2,64,27,64)
                             const float* __restrict__ wskip,  // (2,32,64)
                             const float* __restrict__ bias2,  // c2_bc (64,)
                             const float* __restrict__ biass,  // skip_bc (64,)
                             float* __restrict__ out)
{
    __shared__ float xt[4][6][6][12];
    __shared__ float wl[4][27][64];
    __shared__ float skw[32][64];

    const int tid = threadIdx.x;
    const int co_t = tid >> 4;
    const int v_t = tid & 15;
    const int vz = v_t >> 2;
    const int vy = v_t & 3;

    const int x0 = blockIdx.x * 8;
    const int y0 = blockIdx.y * 4;
    const int n  = blockIdx.z / 23;
    const int z0 = (blockIdx.z % 23) * 4;

    float acc[4][8];
    #pragma unroll
    for (int c = 0; c < 4; ++c)
        #pragma unroll
        for (int j = 0; j < 8; ++j) acc[c][j] = 0.0f;

    // stage skip weights once (read after in-loop barriers, never overwritten)
    for (int idx = tid; idx < 32 * 64; idx += 256)
        ((float*)skw)[idx] = wskip[(size_t)n * 32 * 64 + idx];

    const __hip_bfloat16* hn = hbuf + (size_t)n * 64 * 94 * 94 * 94;

    #pragma unroll 1
    for (int c0 = 0; c0 < 64; c0 += 4) {
        __syncthreads();
        for (int idx = tid; idx < 4 * 6 * 6 * 12; idx += 256) {
            int ci_l = idx / 432;
            int r = idx - ci_l * 432;
            int zz = r / 72; r -= zz * 72;
            int yy = r / 12;
            int xx = r - yy * 12;
            int gz = z0 + zz, gy = y0 + yy, gx = x0 + xx;
            float v = 0.0f;
            if (gz < 94 && gy < 94 && gx < 94)
                v = __bfloat162float(
                    hn[(((size_t)(c0 + ci_l) * 94 + gz) * 94 + gy) * 94 + gx]);
            ((float*)xt)[idx] = v;
        }
        const float* wsrc = wdm + ((size_t)n * 64 + c0) * 27 * 64;
        for (int idx = tid; idx < 4 * 27 * 64; idx += 256)
            ((float*)wl)[idx] = wsrc[idx];
        __syncthreads();

        #pragma unroll 1
        for (int ci_l = 0; ci_l < 4; ++ci_l) {
            #pragma unroll
            for (int kd = 0; kd < 3; ++kd) {
                #pragma unroll
                for (int kh = 0; kh < 3; ++kh) {
                    const float4* row =
                        reinterpret_cast<const float4*>(&xt[ci_l][vz + kd][vy + kh][0]);
                    float4 r0 = row[0], r1 = row[1], r2 = row[2];
                    float xr[12] = {r0.x, r0.y, r0.z, r0.w,
                                    r1.x, r1.y, r1.z, r1.w,
                                    r2.x, r2.y, r2.z, r2.w};
                    const float* wrow = &wl[ci_l][(kd * 3 + kh) * 3][co_t * 4];
                    #pragma unroll
                    for (int kx = 0; kx < 3; ++kx) {
                        float4 wv = *reinterpret_cast<const float4*>(wrow + kx * 64);
                        #pragma unroll
                        for (int j = 0; j < 8; ++j) {
                            float xv = xr[kx + j];
                            acc[0][j] = fmaf(wv.x, xv, acc[0][j]);
                            acc[1][j] = fmaf(wv.y, xv, acc[1][j]);
                            acc[2][j] = fmaf(wv.z, xv, acc[2][j]);
                            acc[3][j] = fmaf(wv.w, xv, acc[3][j]);
                        }
                    }
                }
            }
        }
    }

    // fused skip path: out += sum_ci wskip[ci][co] * x[n,ci,z+2,y+2,x+2]
    // (x reads stay in-bounds: gz,gy <= 93, gx <= 97 < row slack, see analysis)
    {
        const int gz = z0 + vz + 2, gy = y0 + vy + 2;
        const float* xn = x + (size_t)n * 32 * 96 * 96 * 96;
        #pragma unroll 1
        for (int ci = 0; ci < 32; ++ci) {
            const float4 wv = *reinterpret_cast<const float4*>(&skw[ci][co_t * 4]);
            const float* xrow = &xn[(((size_t)ci * 96 + gz) * 96 + gy) * 96 + x0 + 2];
            #pragma unroll
            for (int j = 0; j < 8; ++j) {
                float xv = xrow[j];
                acc[0][j] = fmaf(wv.x, xv, acc[0][j]);
                acc[1][j] = fmaf(wv.y, xv, acc[1][j]);
                acc[2][j] = fmaf(wv.z, xv, acc[2][j]);
                acc[3][j] = fmaf(wv.w, xv, acc[3][j]);
            }
        }
    }

    // epilogue: z/y always valid (92 = 23*4); x tail guarded
    const int oz = z0 + vz, oy = y0 + vy;
    const int co = co_t * 4;
    #pragma unroll
    for (int c = 0; c < 4; ++c) {
        float b = bias2[co + c] + biass[co + c];
        size_t base = ((((size_t)n * 64 + co + c) * 92 + oz) * 92 + oy) * 92 + x0;
        if (x0 + 8 <= 92) {
            float4 o0 = make_float4(leaky(acc[c][0] + b), leaky(acc[c][1] + b),
                                    leaky(acc[c][2] + b), leaky(acc[c][3] + b));
            float4 o1 = make_float4(leaky(acc[c][4] + b), leaky(acc[c][5] + b),
                                    leaky(acc[c][6] + b), leaky(acc[c][7] + b));
            float4* dst = reinterpret_cast<float4*>(out + base);
            dst[0] = o0;
            dst[1] = o1;
        } else {
            for (int j = 0; j < 8 && x0 + j < 92; ++j)
                out[base + j] = leaky(acc[c][j] + b);
        }
    }
}

// -------------------------------------------------------------------------
extern "C" void kernel_launch(void* const* d_in, const int* in_sizes, int n_in,
                              void* d_out, int out_size, void* d_ws, size_t ws_size,
                              hipStream_t stream)
{
    const float* x       = (const float*)d_in[0];
    const float* s       = (const float*)d_in[1];
    const float* skip_w1 = (const float*)d_in[2];
    const float* skip_b1 = (const float*)d_in[3];
    const float* skip_w2 = (const float*)d_in[4];
    const float* skip_b2 = (const float*)d_in[5];
    const float* skip_w3 = (const float*)d_in[6];
    const float* skip_b3 = (const float*)d_in[7];
    const float* skip_wc = (const float*)d_in[8];
    const float* skip_bc = (const float*)d_in[9];
    const float* c1_w1   = (const float*)d_in[10];
    const float* c1_b1   = (const float*)d_in[11];
    const float* c1_w2   = (const float*)d_in[12];
    const float* c1_b2   = (const float*)d_in[13];
    const float* c1_w3   = (const float*)d_in[14];
    const float* c1_b3   = (const float*)d_in[15];
    const float* c1_wc   = (const float*)d_in[16];
    const float* c1_bc   = (const float*)d_in[17];
    const float* c2_w1   = (const float*)d_in[18];
    const float* c2_b1   = (const float*)d_in[19];
    const float* c2_w2   = (const float*)d_in[20];
    const float* c2_b2   = (const float*)d_in[21];
    const float* c2_w3   = (const float*)d_in[22];
    const float* c2_b3   = (const float*)d_in[23];
    const float* c2_wc   = (const float*)d_in[24];
    const float* c2_bc   = (const float*)d_in[25];
    float* out = (float*)d_out;

    // workspace layout
    char* ws = (char*)d_ws;
    __hip_bfloat16* hbuf = (__hip_bfloat16*)ws;          // (2,64,94,94,94) bf16
    size_t off = (size_t)2 * 64 * 94 * 94 * 94 * 2;      // 212,629,504 B (256-aligned)
    float* w_c1 = (float*)(ws + off); off += (size_t)2 * 32 * 27 * 64 * 4;
    float* w_c2 = (float*)(ws + off); off += (size_t)2 * 64 * 27 * 64 * 4;
    float* w_sk = (float*)(ws + off);

    style_weights_kernel<<<dim3(2), dim3(256), 0, stream>>>(
        s, skip_w1, skip_b1, skip_w2, skip_b2, skip_w3, skip_b3, skip_wc,
        w_sk, 64, 64, 32, 1);
    style_weights_kernel<<<dim3(2), dim3(256), 0, stream>>>(
        s, c1_w1, c1_b1, c1_w2, c1_b2, c1_w3, c1_b3, c1_wc,
        w_c1, 64, 64, 32, 27);
    style_weights_kernel<<<dim3(2), dim3(256), 0, stream>>>(
        s, c2_w1, c2_b1, c2_w2, c2_b2, c2_w3, c2_b3, c2_wc,
        w_c2, 128, 128, 64, 27);

    conv1_kernel<<<dim3(12, 24, 48), dim3(256), 0, stream>>>(x, w_c1, c1_bc, hbuf);
    conv2_kernel<<<dim3(12, 23, 46), dim3(256), 0, stream>>>(hbuf, x, w_c2, w_sk,
                                                             c2_bc, skip_bc, out);
}